// Round 5
// baseline (314.579 us; speedup 1.0000x reference)
//
#include <hip/hip_runtime.h>
#include <hip/hip_bf16.h>

// Complex ConvLSTM cell. Inputs f32, output f32 (verified R3/R4, absmax 0.0625).
//   Zp: halo-padded packed activations, [b][y' 0..65][x' 0..65][cin 0..255] bf16
//   Wp[n][tap][cin]: n = part*64+ch, parts {yr_i,yi_i,yr_o,yi_o,yr_c,yi_c};
//       yr -> [Wr ; -Wi], yi -> [Wi ; Wr].
//   conv_gemm: 128ch x 128px tile, global_load_lds(16B), XOR-swizzled LDS,
//       dy-grouped taps. At the ~940 TF m97-structure plateau (R4 measured).
//   epilogue: vectorized x4 gate math -> h_new, c_new (f32).

typedef __attribute__((ext_vector_type(8))) short short8;
typedef __attribute__((ext_vector_type(4))) float floatx4;
typedef __attribute__((ext_vector_type(4))) float float4v;
typedef __attribute__((ext_vector_type(4))) unsigned short ushort4v;

#define MTOT   65536
#define HSIZE  8388608

__device__ __forceinline__ short f2bf(float f) {
  __hip_bfloat16 h = __float2bfloat16(f);
  return *reinterpret_cast<short*>(&h);
}
__device__ __forceinline__ float bf2f(unsigned short u) {
  return __uint_as_float(((unsigned)u) << 16);
}

__device__ __forceinline__ void gload16(const short* g, void* lds) {
  __builtin_amdgcn_global_load_lds(
      (__attribute__((address_space(1))) void*)(g),
      (__attribute__((address_space(3))) void*)(lds), 16, 0, 0);
}

// ---------------------------------------------------------------- pack Z + halo
// blocks 0..4095: transpose-pack one (b, srcSel, half, y) 64ch x 64x tile.
// blocks 4096..4615: zero the halo ring.
__global__ __launch_bounds__(256) void pack_z_kernel(
    const float* __restrict__ xs, const float* __restrict__ hs,
    short* __restrict__ Zp) {
  __shared__ short tile[64 * 72];
  int bid = blockIdx.x;
  int t = threadIdx.x;
  if (bid >= 4096) {                         // halo zero
    int g = (bid - 4096) * 256 + t;          // 520*256 = 133,120 = 4160 px * 32
    int s = g & 31, pix = g >> 5;
    int b = pix / 260;
    int r = pix - b * 260;
    int yp, xp;
    if (r < 66)       { yp = 0;  xp = r; }
    else if (r < 132) { yp = 65; xp = r - 66; }
    else { int r2 = r - 132; yp = 1 + (r2 >> 1); xp = (r2 & 1) * 65; }
    short8 z;
#pragma unroll
    for (int q = 0; q < 8; ++q) z[q] = 0;
    *(short8*)(Zp + (((size_t)(b * 66 + yp) * 66 + xp) * 256 + s * 8)) = z;
    return;
  }
  int y      = bid & 63;
  int half   = (bid >> 6) & 1;
  int srcSel = (bid >> 7) & 1;
  int b      = bid >> 8;
  const float* src = srcSel ? hs : xs;
  int chBase  = half * 64;
  int cinBase = half * 128 + srcSel * 64;
  int x4 = t & 15, chq = t >> 4;
#pragma unroll
  for (int p = 0; p < 4; ++p) {
    int ch = p * 16 + chq;
    float4v f = *(const float4v*)(src + (size_t)(b * 128 + chBase + ch) * 4096 + y * 64 + x4 * 4);
#pragma unroll
    for (int e = 0; e < 4; ++e)
      tile[(x4 * 4 + e) * 72 + ch] = f2bf(f[e]);
  }
  __syncthreads();
  int x = t >> 2, seg = t & 3;
  short8 v0 = *(const short8*)(tile + x * 72 + seg * 16);
  short8 v1 = *(const short8*)(tile + x * 72 + seg * 16 + 8);
  size_t outp = ((size_t)(b * 66 + y + 1) * 66 + x + 1) * 256 + cinBase + seg * 16;
  *(short8*)(Zp + outp)     = v0;
  *(short8*)(Zp + outp + 8) = v1;
}

// ---------------------------------------------------------------- pack W + bias
// thread <-> (n, cin): reads 9 contiguous f32, writes coalesced-across-cin.
__global__ __launch_bounds__(256) void pack_w_kernel(
    const float* __restrict__ Wr_i, const float* __restrict__ Wi_i,
    const float* __restrict__ Wr_o, const float* __restrict__ Wi_o,
    const float* __restrict__ Wr_c, const float* __restrict__ Wi_c,
    const float* __restrict__ br_i, const float* __restrict__ bi_i,
    const float* __restrict__ br_o, const float* __restrict__ bi_o,
    const float* __restrict__ br_c, const float* __restrict__ bi_c,
    short* __restrict__ Wp, float* __restrict__ bias) {
  int g = blockIdx.x * 256 + threadIdx.x;    // 384 * 256
  int cin = g & 255;
  int n   = g >> 8;
  int part = n >> 6, ch = n & 63;
  const float *Wr, *Wi;
  if (part < 2)      { Wr = Wr_i; Wi = Wi_i; }
  else if (part < 4) { Wr = Wr_o; Wi = Wi_o; }
  else               { Wr = Wr_c; Wi = Wi_c; }
  int im = part & 1;
  int ci = cin & 127;
  int second = cin >> 7;
  const float* src = (im ? (second ? Wr : Wi) : (second ? Wi : Wr)) + (ch * 128 + ci) * 9;
  float sgn = (!im && second) ? -1.f : 1.f;
#pragma unroll
  for (int tap = 0; tap < 9; ++tap)
    Wp[(size_t)(n * 9 + tap) * 256 + cin] = f2bf(sgn * src[tap]);
  if (cin == 0) {
    const float* bs = (part == 0) ? br_i : (part == 1) ? bi_i : (part == 2) ? br_o
                    : (part == 3) ? bi_o : (part == 4) ? br_c : bi_c;
    bias[n] = bs[ch];
  }
}

// ---------------------------------------------------------------- implicit GEMM
// 128ch x 128px tile, 4 waves (each 64x64), K = 9 taps x 256 cin.
// LDS: As[row][slot] 16B slots, slot p holds k-group p^(row&7);
//      Bs[r2][col][slot], slot p holds group p^(col&7). global_load_lds staged.
__global__ __launch_bounds__(256, 3) void conv_gemm(
    const short* __restrict__ Z, const short* __restrict__ Wp,
    const float* __restrict__ bias, __hip_bfloat16* __restrict__ gates) {
  __shared__ short8 As[1024];   // 16 KiB
  __shared__ short8 Bs[1056];   // 16.5 KiB

  const int tid = threadIdx.x;
  const int wv = tid >> 6, lane = tid & 63;
  const int l15 = lane & 15, l4 = lane >> 4;
  const int m0 = blockIdx.x * 128;
  const int n0 = blockIdx.y * 128;
  const int b  = m0 >> 12;
  const int y0 = (m0 >> 6) & 63;
  const int wch = (wv & 1) * 64;
  const int r2w = wv >> 1;

  floatx4 acc[4][4];
#pragma unroll
  for (int i = 0; i < 4; ++i)
#pragma unroll
    for (int j = 0; j < 4; ++j)
#pragma unroll
      for (int r = 0; r < 4; ++r) acc[i][j][r] = 0.f;

  for (int dy = -1; dy <= 1; ++dy) {
    for (int c0 = 0; c0 < 256; c0 += 64) {
#pragma unroll
      for (int it = 0; it < 5; ++it) {
        int idx = tid + it * 256;
        if (idx < 1056) {
          int r2  = (idx >= 528) ? 1 : 0;
          int rem = idx - r2 * 528;
          int col = rem >> 3, p = rem & 7;
          int g   = p ^ (col & 7);
          int ygl = b * 66 + y0 + dy + 1 + r2;
          gload16(Z + ((size_t)(ygl * 66 + col) * 256 + c0 + g * 8),
                  (void*)(Bs + (it * 256 + wv * 64)));
        }
      }
      for (int dx = -1; dx <= 1; ++dx) {
        int tap = (dy + 1) * 3 + (dx + 1);
#pragma unroll
        for (int it = 0; it < 4; ++it) {
          int idx = tid + it * 256;
          int row = idx >> 3, p = idx & 7;
          int g   = p ^ (row & 7);
          gload16(Wp + ((size_t)((n0 + row) * 9 + tap) * 256 + c0 + g * 8),
                  (void*)(As + (it * 256 + wv * 64)));
        }
        __syncthreads();
#pragma unroll
        for (int kk = 0; kk < 2; ++kk) {
          int kg = kk * 4 + l4;
          short8 a[4], bf[4];
#pragma unroll
          for (int i = 0; i < 4; ++i) {
            int row = wch + i * 16 + l15;
            a[i] = As[row * 8 + (kg ^ (row & 7))];
          }
#pragma unroll
          for (int j = 0; j < 4; ++j) {
            int col = j * 16 + l15 + dx + 1;
            bf[j] = Bs[r2w * 528 + col * 8 + (kg ^ (col & 7))];
          }
#pragma unroll
          for (int i = 0; i < 4; ++i)
#pragma unroll
            for (int j = 0; j < 4; ++j)
              acc[i][j] = __builtin_amdgcn_mfma_f32_16x16x32_bf16(a[i], bf[j], acc[i][j], 0, 0, 0);
        }
        __syncthreads();
      }
    }
  }
#pragma unroll
  for (int i = 0; i < 4; ++i)
#pragma unroll
    for (int j = 0; j < 4; ++j)
#pragma unroll
      for (int r = 0; r < 4; ++r) {
        int ch = n0 + wch + i * 16 + l4 * 4 + r;
        int px = m0 + r2w * 64 + j * 16 + l15;
        gates[(size_t)ch * MTOT + px] = __float2bfloat16(acc[i][j][r] + bias[ch]);
      }
}

// ---------------------------------------------------------------- epilogue (x4 vec)
__device__ __forceinline__ float fsig(float v) { return 1.f / (1.f + __expf(-v)); }
__device__ __forceinline__ float ftanh(float v) {
  float e = __expf(2.f * v);
  return 1.f - 2.f / (e + 1.f);
}

__global__ __launch_bounds__(256) void epilogue_kernel(
    const unsigned short* __restrict__ gates,
    const float* __restrict__ x,
    const float* __restrict__ c_prev,
    float* __restrict__ out) {
  int g = blockIdx.x * 256 + threadIdx.x;    // 64 ch * 16384 quads
  int q  = g & 16383;
  int ch = g >> 14;
  int m4 = q * 4;
  int b = m4 >> 12, sp = m4 & 4095;
  size_t base = (size_t)(b * 128 + ch) * 4096 + sp;
  ushort4v gv[6];
#pragma unroll
  for (int p = 0; p < 6; ++p)
    gv[p] = *(const ushort4v*)(gates + (size_t)(p * 64 + ch) * MTOT + m4);
  float4v xr = *(const float4v*)(x + base);
  float4v xi = *(const float4v*)(x + base + 64 * 4096);
  float4v cr = *(const float4v*)(c_prev + base);
  float4v ci = *(const float4v*)(c_prev + base + 64 * 4096);
  float4v hr, hi, onr, oni;
#pragma unroll
  for (int e = 0; e < 4; ++e) {
    float i_r = fsig(bf2f(gv[0][e])), i_i = fsig(bf2f(gv[1][e]));
    float o_r = fsig(bf2f(gv[2][e])), o_i = fsig(bf2f(gv[3][e]));
    float ct_r = ftanh(bf2f(gv[4][e])), ct_i = ftanh(bf2f(gv[5][e]));
    float cnr = xr[e] * cr[e] - xi[e] * ci[e] + i_r * ct_r - i_i * ct_i;
    float cni = xr[e] * ci[e] + xi[e] * cr[e] + i_r * ct_i + i_i * ct_r;
    float tr = ftanh(cnr), ti = ftanh(cni);
    hr[e] = o_r * tr - o_i * ti;
    hi[e] = o_r * ti + o_i * tr;
    onr[e] = cnr; oni[e] = cni;
  }
  *(float4v*)(out + base)                     = hr;
  *(float4v*)(out + base + 64 * 4096)         = hi;
  *(float4v*)(out + HSIZE + base)             = onr;
  *(float4v*)(out + HSIZE + base + 64 * 4096) = oni;
}

// ---------------------------------------------------------------- launch
extern "C" void kernel_launch(void* const* d_in, const int* in_sizes, int n_in,
                              void* d_out, int out_size, void* d_ws, size_t ws_size,
                              hipStream_t stream) {
  // inputs: 0 x, 1 h_prev, 2 c_prev,
  //         3 Wr_i, 4 Wi_i, 5 br_i, 6 bi_i,  7..10 f-gate (unused),
  //        11 Wr_o,12 Wi_o,13 br_o,14 bi_o, 15 Wr_c,16 Wi_c,17 br_c,18 bi_c
  const float* x = (const float*)d_in[0];
  const float* h = (const float*)d_in[1];

  char* ws = (char*)d_ws;
  short* Zp   = (short*)ws;                          // 35,684,352 B
  short* Wp   = (short*)(ws + 35684352);             //  1,769,472 B
  float* bias = (float*)(ws + 37453824);             //      1,536 B
  __hip_bfloat16* gates = (__hip_bfloat16*)(ws + 37455360); // 50,331,648 B

  pack_z_kernel<<<4616, 256, 0, stream>>>(x, h, Zp);
  pack_w_kernel<<<384, 256, 0, stream>>>(
      (const float*)d_in[3], (const float*)d_in[4],
      (const float*)d_in[11], (const float*)d_in[12],
      (const float*)d_in[15], (const float*)d_in[16],
      (const float*)d_in[5], (const float*)d_in[6],
      (const float*)d_in[13], (const float*)d_in[14],
      (const float*)d_in[17], (const float*)d_in[18],
      Wp, bias);
  conv_gemm<<<dim3(512, 3), 256, 0, stream>>>(Zp, Wp, bias, gates);
  epilogue_kernel<<<4096, 256, 0, stream>>>(
      (const unsigned short*)gates, (const float*)d_in[0], (const float*)d_in[2],
      (float*)d_out);
}